// Round 7
// baseline (217.739 us; speedup 1.0000x reference)
//
#include <hip/hip_runtime.h>
#include <hip/hip_fp16.h>

// SSIM loss v6: v5 structure with unions removed (value-level bit_cast ->
// no scratch spill), hardcoded Gaussian weights (SGPR operands), and
// fast rcp for the per-pixel divide. fp16-packed LDS h-stats (26.25 KiB),
// packed-half2 vertical conv.
// Inputs: img1, img2 float32 [16,3,512,512]. Output: scalar float32.

#define TSX   64
#define TSY   32
#define LTY   42               // TSY + 10 rows of horizontal stats
#define IMG   512
#define NPLANES 48
#define NPIX  (48*512*512)

// Normalized 11-tap Gaussian (sigma=1.5), computed in double precision.
constexpr float GW[11] = {
    0.00102837f, 0.00759877f, 0.03600077f, 0.10936070f, 0.21300553f,
    0.26601174f,
    0.21300553f, 0.10936070f, 0.03600077f, 0.00759877f, 0.00102837f
};

__device__ __forceinline__ void load4g(const float* __restrict__ row, int gx,
                                       float* dst) {
    if (gx >= 0 && gx + 3 < IMG) {
        float4 v = *reinterpret_cast<const float4*>(row + gx);
        dst[0] = v.x; dst[1] = v.y; dst[2] = v.z; dst[3] = v.w;
    } else {
#pragma unroll
        for (int j = 0; j < 4; ++j)
            dst[j] = ((unsigned)(gx + j) < (unsigned)IMG) ? row[gx + j] : 0.f;
    }
}

__device__ __forceinline__ unsigned packh2(float a, float b) {
    return __builtin_bit_cast(unsigned, __floats2half2_rn(a, b));
}

__global__ void __launch_bounds__(256, 6)
ssim_kernel(const float* __restrict__ img1,
            const float* __restrict__ img2,
            float* __restrict__ acc)
{
    __shared__ __align__(16) uint2 hh[5][LTY][TSX / 4];   // 26.25 KiB
    __shared__ float wsum[4];

    const int tid = threadIdx.x;
    const int bx  = blockIdx.x;
    const int by  = blockIdx.y;
    const size_t pbase = (size_t)blockIdx.z * IMG * IMG;
    const float* __restrict__ p1 = img1 + pbase;
    const float* __restrict__ p2 = img2 + pbase;

    const bool interior_x = (bx >= 1 && bx <= 6);   // block-uniform

    // ---------- Phase A: horizontal 11-tap, 4 output cols per item ----------
    for (int i = tid; i < LTY * 16; i += 256) {
        const int r  = i >> 4;
        const int g  = i & 15;
        const int gy = by * TSY - 5 + r;

        float in1[20], in2[20];
        if ((unsigned)gy < (unsigned)IMG) {
            const float* row1 = p1 + (size_t)gy * IMG;
            const float* row2 = p2 + (size_t)gy * IMG;
            const int gx0 = bx * TSX + g * 4 - 8;
            if (interior_x) {
#pragma unroll
                for (int b = 0; b < 5; ++b) {
                    float4 v = *reinterpret_cast<const float4*>(row1 + gx0 + b * 4);
                    in1[b*4+0] = v.x; in1[b*4+1] = v.y; in1[b*4+2] = v.z; in1[b*4+3] = v.w;
                    float4 u = *reinterpret_cast<const float4*>(row2 + gx0 + b * 4);
                    in2[b*4+0] = u.x; in2[b*4+1] = u.y; in2[b*4+2] = u.z; in2[b*4+3] = u.w;
                }
            } else {
#pragma unroll
                for (int b = 0; b < 5; ++b) {
                    load4g(row1, gx0 + b * 4, &in1[b * 4]);
                    load4g(row2, gx0 + b * 4, &in2[b * 4]);
                }
            }
        } else {
#pragma unroll
            for (int t = 0; t < 20; ++t) { in1[t] = 0.f; in2[t] = 0.f; }
        }

        float s11[14], s22[14], s12[14];
#pragma unroll
        for (int t = 0; t < 14; ++t) {
            float a = in1[t + 3], b = in2[t + 3];
            s11[t] = a * a;
            s22[t] = b * b;
            s12[t] = a * b;
        }

        float m1v[4], m2v[4], a11v[4], a22v[4], a12v[4];
#pragma unroll
        for (int q = 0; q < 4; ++q) {
            float m1 = 0.f, m2 = 0.f, a11 = 0.f, a22 = 0.f, a12 = 0.f;
#pragma unroll
            for (int k = 0; k < 11; ++k) {
                const float wk = GW[k];
                m1  += wk * in1[3 + q + k];
                m2  += wk * in2[3 + q + k];
                a11 += wk * s11[q + k];
                a22 += wk * s22[q + k];
                a12 += wk * s12[q + k];
            }
            m1v[q] = m1; m2v[q] = m2; a11v[q] = a11; a22v[q] = a22; a12v[q] = a12;
        }

        hh[0][r][g] = make_uint2(packh2(m1v[0],  m1v[1]),  packh2(m1v[2],  m1v[3]));
        hh[1][r][g] = make_uint2(packh2(m2v[0],  m2v[1]),  packh2(m2v[2],  m2v[3]));
        hh[2][r][g] = make_uint2(packh2(a11v[0], a11v[1]), packh2(a11v[2], a11v[3]));
        hh[3][r][g] = make_uint2(packh2(a22v[0], a22v[1]), packh2(a22v[2], a22v[3]));
        hh[4][r][g] = make_uint2(packh2(a12v[0], a12v[1]), packh2(a12v[2], a12v[3]));
    }
    __syncthreads();

    // ----- Phase B: vertical 11-tap (packed half2 FMA) + SSIM, 4c x 2r -----
    const float C1 = 1e-4f;
    const float C2 = 9e-4f;
    float local = 0.f;
    {
        const int cg = tid & 15;       // uint2 col group: px cols 4cg..4cg+3
        const int rg = tid >> 4;       // 0..15 -> output rows rg*2, rg*2+1
        const int r0 = rg * 2;

        const __half2 zero2 = __float2half2_rn(0.f);
        __half2 ac[2][5][2];
#pragma unroll
        for (int q = 0; q < 2; ++q)
#pragma unroll
            for (int s = 0; s < 5; ++s) {
                ac[q][s][0] = zero2; ac[q][s][1] = zero2;
            }

#pragma unroll
        for (int rr = 0; rr < 12; ++rr) {
#pragma unroll
            for (int s = 0; s < 5; ++s) {
                const uint2 rd = hh[s][r0 + rr][cg];
                const __half2 lo = __builtin_bit_cast(__half2, rd.x);
                const __half2 hi = __builtin_bit_cast(__half2, rd.y);
#pragma unroll
                for (int q = 0; q < 2; ++q) {
                    const int k = rr - q;
                    if (k >= 0 && k <= 10) {          // compile-time after unroll
                        const __half2 wk = __float2half2_rn(GW[k]);
                        ac[q][s][0] = __hfma2(wk, lo, ac[q][s][0]);
                        ac[q][s][1] = __hfma2(wk, hi, ac[q][s][1]);
                    }
                }
            }
        }

#pragma unroll
        for (int q = 0; q < 2; ++q) {
#pragma unroll
            for (int hp = 0; hp < 2; ++hp) {
                float2 mu1 = __half22float2(ac[q][0][hp]);
                float2 mu2 = __half22float2(ac[q][1][hp]);
                float2 v11 = __half22float2(ac[q][2][hp]);
                float2 v22 = __half22float2(ac[q][3][hp]);
                float2 v12 = __half22float2(ac[q][4][hp]);
#pragma unroll
                for (int e = 0; e < 2; ++e) {
                    float m1 = e ? mu1.y : mu1.x;
                    float m2 = e ? mu2.y : mu2.x;
                    float s1 = e ? v11.y : v11.x;
                    float s2 = e ? v22.y : v22.x;
                    float sx = e ? v12.y : v12.x;
                    float mu1sq = m1 * m1;
                    float mu2sq = m2 * m2;
                    float mu12  = m1 * m2;
                    float sig1  = s1 - mu1sq;
                    float sig2  = s2 - mu2sq;
                    float sig12 = sx - mu12;
                    float num = (2.f * mu12 + C1) * (2.f * sig12 + C2);
                    float den = (mu1sq + mu2sq + C1) * (sig1 + sig2 + C2);
                    local += num * __builtin_amdgcn_rcpf(den);
                }
            }
        }
    }

    // ---------- block reduction ----------
#pragma unroll
    for (int off = 32; off > 0; off >>= 1)
        local += __shfl_down(local, off, 64);
    if ((tid & 63) == 0) wsum[tid >> 6] = local;
    __syncthreads();
    if (tid == 0) {
        float t = wsum[0] + wsum[1] + wsum[2] + wsum[3];
        atomicAdd(acc, t);
    }
}

__global__ void zero_acc_kernel(float* acc) {
    if (threadIdx.x == 0) acc[0] = 0.f;
}

__global__ void finalize_kernel(const float* __restrict__ acc,
                                float* __restrict__ out) {
    if (threadIdx.x == 0)
        out[0] = 1.0f - acc[0] * (1.0f / (float)NPIX);
}

extern "C" void kernel_launch(void* const* d_in, const int* in_sizes, int n_in,
                              void* d_out, int out_size, void* d_ws, size_t ws_size,
                              hipStream_t stream) {
    const float* img1 = (const float*)d_in[0];
    const float* img2 = (const float*)d_in[1];
    float* out = (float*)d_out;
    float* acc = (float*)d_ws;

    zero_acc_kernel<<<1, 64, 0, stream>>>(acc);
    dim3 grid(IMG / TSX, IMG / TSY, NPLANES);   // (8, 16, 48) = 6144 blocks
    ssim_kernel<<<grid, 256, 0, stream>>>(img1, img2, acc);
    finalize_kernel<<<1, 64, 0, stream>>>(acc, out);
}

// Round 8
// 192.277 us; speedup vs baseline: 1.1324x; 1.1324x over previous
//
#include <hip/hip_runtime.h>
#include <hip/hip_fp16.h>

// SSIM loss v7: v6 with the spill-inducing __launch_bounds__(256,6) relaxed
// to (256,4). (256,6) forced the <=64-VGPR occupancy step -> allocator capped
// at 40 VGPR and spilled ~55MB/dispatch to scratch (seen as WRITE_SIZE).
// (256,4) gives a 128-VGPR budget: no spill, 4 blocks/CU via 26.25KiB LDS,
// 16 waves/CU.
// Inputs: img1, img2 float32 [16,3,512,512]. Output: scalar float32.

#define TSX   64
#define TSY   32
#define LTY   42               // TSY + 10 rows of horizontal stats
#define IMG   512
#define NPLANES 48
#define NPIX  (48*512*512)

// Normalized 11-tap Gaussian (sigma=1.5), computed in double precision.
constexpr float GW[11] = {
    0.00102837f, 0.00759877f, 0.03600077f, 0.10936070f, 0.21300553f,
    0.26601174f,
    0.21300553f, 0.10936070f, 0.03600077f, 0.00759877f, 0.00102837f
};

__device__ __forceinline__ void load4g(const float* __restrict__ row, int gx,
                                       float* dst) {
    if (gx >= 0 && gx + 3 < IMG) {
        float4 v = *reinterpret_cast<const float4*>(row + gx);
        dst[0] = v.x; dst[1] = v.y; dst[2] = v.z; dst[3] = v.w;
    } else {
#pragma unroll
        for (int j = 0; j < 4; ++j)
            dst[j] = ((unsigned)(gx + j) < (unsigned)IMG) ? row[gx + j] : 0.f;
    }
}

__device__ __forceinline__ unsigned packh2(float a, float b) {
    return __builtin_bit_cast(unsigned, __floats2half2_rn(a, b));
}

__global__ void __launch_bounds__(256, 4)
ssim_kernel(const float* __restrict__ img1,
            const float* __restrict__ img2,
            float* __restrict__ acc)
{
    __shared__ __align__(16) uint2 hh[5][LTY][TSX / 4];   // 26.25 KiB
    __shared__ float wsum[4];

    const int tid = threadIdx.x;
    const int bx  = blockIdx.x;
    const int by  = blockIdx.y;
    const size_t pbase = (size_t)blockIdx.z * IMG * IMG;
    const float* __restrict__ p1 = img1 + pbase;
    const float* __restrict__ p2 = img2 + pbase;

    const bool interior_x = (bx >= 1 && bx <= 6);   // block-uniform

    // ---------- Phase A: horizontal 11-tap, 4 output cols per item ----------
    for (int i = tid; i < LTY * 16; i += 256) {
        const int r  = i >> 4;
        const int g  = i & 15;
        const int gy = by * TSY - 5 + r;

        float in1[20], in2[20];
        if ((unsigned)gy < (unsigned)IMG) {
            const float* row1 = p1 + (size_t)gy * IMG;
            const float* row2 = p2 + (size_t)gy * IMG;
            const int gx0 = bx * TSX + g * 4 - 8;
            if (interior_x) {
#pragma unroll
                for (int b = 0; b < 5; ++b) {
                    float4 v = *reinterpret_cast<const float4*>(row1 + gx0 + b * 4);
                    in1[b*4+0] = v.x; in1[b*4+1] = v.y; in1[b*4+2] = v.z; in1[b*4+3] = v.w;
                    float4 u = *reinterpret_cast<const float4*>(row2 + gx0 + b * 4);
                    in2[b*4+0] = u.x; in2[b*4+1] = u.y; in2[b*4+2] = u.z; in2[b*4+3] = u.w;
                }
            } else {
#pragma unroll
                for (int b = 0; b < 5; ++b) {
                    load4g(row1, gx0 + b * 4, &in1[b * 4]);
                    load4g(row2, gx0 + b * 4, &in2[b * 4]);
                }
            }
        } else {
#pragma unroll
            for (int t = 0; t < 20; ++t) { in1[t] = 0.f; in2[t] = 0.f; }
        }

        float s11[14], s22[14], s12[14];
#pragma unroll
        for (int t = 0; t < 14; ++t) {
            float a = in1[t + 3], b = in2[t + 3];
            s11[t] = a * a;
            s22[t] = b * b;
            s12[t] = a * b;
        }

        float m1v[4], m2v[4], a11v[4], a22v[4], a12v[4];
#pragma unroll
        for (int q = 0; q < 4; ++q) {
            float m1 = 0.f, m2 = 0.f, a11 = 0.f, a22 = 0.f, a12 = 0.f;
#pragma unroll
            for (int k = 0; k < 11; ++k) {
                const float wk = GW[k];
                m1  += wk * in1[3 + q + k];
                m2  += wk * in2[3 + q + k];
                a11 += wk * s11[q + k];
                a22 += wk * s22[q + k];
                a12 += wk * s12[q + k];
            }
            m1v[q] = m1; m2v[q] = m2; a11v[q] = a11; a22v[q] = a22; a12v[q] = a12;
        }

        hh[0][r][g] = make_uint2(packh2(m1v[0],  m1v[1]),  packh2(m1v[2],  m1v[3]));
        hh[1][r][g] = make_uint2(packh2(m2v[0],  m2v[1]),  packh2(m2v[2],  m2v[3]));
        hh[2][r][g] = make_uint2(packh2(a11v[0], a11v[1]), packh2(a11v[2], a11v[3]));
        hh[3][r][g] = make_uint2(packh2(a22v[0], a22v[1]), packh2(a22v[2], a22v[3]));
        hh[4][r][g] = make_uint2(packh2(a12v[0], a12v[1]), packh2(a12v[2], a12v[3]));
    }
    __syncthreads();

    // ----- Phase B: vertical 11-tap (packed half2 FMA) + SSIM, 4c x 2r -----
    const float C1 = 1e-4f;
    const float C2 = 9e-4f;
    float local = 0.f;
    {
        const int cg = tid & 15;       // uint2 col group: px cols 4cg..4cg+3
        const int rg = tid >> 4;       // 0..15 -> output rows rg*2, rg*2+1
        const int r0 = rg * 2;

        const __half2 zero2 = __float2half2_rn(0.f);
        __half2 ac[2][5][2];
#pragma unroll
        for (int q = 0; q < 2; ++q)
#pragma unroll
            for (int s = 0; s < 5; ++s) {
                ac[q][s][0] = zero2; ac[q][s][1] = zero2;
            }

#pragma unroll
        for (int rr = 0; rr < 12; ++rr) {
#pragma unroll
            for (int s = 0; s < 5; ++s) {
                const uint2 rd = hh[s][r0 + rr][cg];
                const __half2 lo = __builtin_bit_cast(__half2, rd.x);
                const __half2 hi = __builtin_bit_cast(__half2, rd.y);
#pragma unroll
                for (int q = 0; q < 2; ++q) {
                    const int k = rr - q;
                    if (k >= 0 && k <= 10) {          // compile-time after unroll
                        const __half2 wk = __float2half2_rn(GW[k]);
                        ac[q][s][0] = __hfma2(wk, lo, ac[q][s][0]);
                        ac[q][s][1] = __hfma2(wk, hi, ac[q][s][1]);
                    }
                }
            }
        }

#pragma unroll
        for (int q = 0; q < 2; ++q) {
#pragma unroll
            for (int hp = 0; hp < 2; ++hp) {
                float2 mu1 = __half22float2(ac[q][0][hp]);
                float2 mu2 = __half22float2(ac[q][1][hp]);
                float2 v11 = __half22float2(ac[q][2][hp]);
                float2 v22 = __half22float2(ac[q][3][hp]);
                float2 v12 = __half22float2(ac[q][4][hp]);
#pragma unroll
                for (int e = 0; e < 2; ++e) {
                    float m1 = e ? mu1.y : mu1.x;
                    float m2 = e ? mu2.y : mu2.x;
                    float s1 = e ? v11.y : v11.x;
                    float s2 = e ? v22.y : v22.x;
                    float sx = e ? v12.y : v12.x;
                    float mu1sq = m1 * m1;
                    float mu2sq = m2 * m2;
                    float mu12  = m1 * m2;
                    float sig1  = s1 - mu1sq;
                    float sig2  = s2 - mu2sq;
                    float sig12 = sx - mu12;
                    float num = (2.f * mu12 + C1) * (2.f * sig12 + C2);
                    float den = (mu1sq + mu2sq + C1) * (sig1 + sig2 + C2);
                    local += num * __builtin_amdgcn_rcpf(den);
                }
            }
        }
    }

    // ---------- block reduction ----------
#pragma unroll
    for (int off = 32; off > 0; off >>= 1)
        local += __shfl_down(local, off, 64);
    if ((tid & 63) == 0) wsum[tid >> 6] = local;
    __syncthreads();
    if (tid == 0) {
        float t = wsum[0] + wsum[1] + wsum[2] + wsum[3];
        atomicAdd(acc, t);
    }
}

__global__ void zero_acc_kernel(float* acc) {
    if (threadIdx.x == 0) acc[0] = 0.f;
}

__global__ void finalize_kernel(const float* __restrict__ acc,
                                float* __restrict__ out) {
    if (threadIdx.x == 0)
        out[0] = 1.0f - acc[0] * (1.0f / (float)NPIX);
}

extern "C" void kernel_launch(void* const* d_in, const int* in_sizes, int n_in,
                              void* d_out, int out_size, void* d_ws, size_t ws_size,
                              hipStream_t stream) {
    const float* img1 = (const float*)d_in[0];
    const float* img2 = (const float*)d_in[1];
    float* out = (float*)d_out;
    float* acc = (float*)d_ws;

    zero_acc_kernel<<<1, 64, 0, stream>>>(acc);
    dim3 grid(IMG / TSX, IMG / TSY, NPLANES);   // (8, 16, 48) = 6144 blocks
    ssim_kernel<<<grid, 256, 0, stream>>>(img1, img2, acc);
    finalize_kernel<<<1, 64, 0, stream>>>(acc, out);
}